// Round 8
// baseline (189.988 us; speedup 1.0000x reference)
//
#include <hip/hip_runtime.h>

#define D 128
#define K 64

typedef __attribute__((ext_vector_type(8))) short short8;   // 8 bf16 in 4 VGPRs
typedef __attribute__((ext_vector_type(2))) int int2v;      // 4 bf16 in 2 VGPRs
typedef __attribute__((ext_vector_type(4))) float f32x4;

// HW packed f32x2 -> bf16x2 (RNE). No builtin on gfx950 -> asm.
__device__ inline int cvt_pk_bf16(float lo, float hi) {
  int r;
  asm("v_cvt_pk_bf16_f32 %0, %1, %2" : "=v"(r) : "v"(lo), "v"(hi));
  return r;
}

// DPP row_ror allreduce (16-lane rows = lid groups). Pure VALU, no DS pipe.
template<int CTRL>
__device__ inline float dpp_ror(float x) {
  return __builtin_bit_cast(float, __builtin_amdgcn_update_dpp(
      0, __builtin_bit_cast(int, x), CTRL, 0xF, 0xF, true));
}
__device__ inline float rowsum16(float v) {
  v += dpp_ror<0x121>(v);
  v += dpp_ror<0x122>(v);
  v += dpp_ror<0x124>(v);
  v += dpp_ror<0x128>(v);
  return v;
}
__device__ inline float rowmax16(float v) {
  v = fmaxf(v, dpp_ror<0x121>(v));
  v = fmaxf(v, dpp_ror<0x122>(v));
  v = fmaxf(v, dpp_ror<0x124>(v));
  v = fmaxf(v, dpp_ror<0x128>(v));
  return v;
}

// Load tile t's 16x128 f32 rows, fully coalesced AND non-temporal: x is
// streamed exactly once; nt keeps the fill's dirty L2/L3 lines in place so
// HBM serves pure reads during main (round-7 confirmed: -11 us).
#define LOADX(dst, t) do {                                                  \
    const f32x4* xb = (const f32x4*)(x + (size_t)(t) * (16 * D)) + lane;    \
    _Pragma("unroll") for (int p = 0; p < 8; ++p)                           \
      dst[p] = __builtin_nontemporal_load(xb + p * 64);                     \
  } while (0)

// Pack f32->bf16 and stage into this wave's LDS tile (row-XOR chunk swizzle).
#define PACKX(src) do {                                                     \
    _Pragma("unroll") for (int p = 0; p < 8; ++p) {                         \
      f32x4 v = src[p];                                                     \
      int2v s;                                                              \
      s[0] = cvt_pk_bf16(v[0], v[1]);                                       \
      s[1] = cvt_pk_bf16(v[2], v[3]);                                       \
      int r = 2 * p + hi;                                                   \
      *(int2v*)(amem + r * 256 + ((wc ^ r) << 4) + wh * 8) = s;             \
    }                                                                       \
  } while (0)

// ds_read A fragments, 16 MFMA, online-entropy epilogue -> hacc.
#define TILE_COMPUTE() do {                                                 \
    f32x4 acc[4];                                                           \
    _Pragma("unroll") for (int jt = 0; jt < 4; ++jt)                        \
      acc[jt] = (f32x4){0.f, 0.f, 0.f, 0.f};                                \
    _Pragma("unroll") for (int kk = 0; kk < 4; ++kk) {                      \
      short8 afrag = *(const short8*)(amem + ra[kk]);                       \
      _Pragma("unroll") for (int jt = 0; jt < 4; ++jt)                      \
        acc[jt] = __builtin_amdgcn_mfma_f32_16x16x32_bf16(                  \
            afrag, bsm[cbase[kk] + jt * 256], acc[jt], 0, 0, 0);            \
    }                                                                       \
    _Pragma("unroll") for (int r = 0; r < 4; ++r) {                         \
      float s0 = acc[0][r] - mn[0];                                         \
      float s1 = acc[1][r] - mn[1];                                         \
      float s2 = acc[2][r] - mn[2];                                         \
      float s3 = acc[3][r] - mn[3];                                         \
      float mx = rowmax16(fmaxf(fmaxf(s0, s1), fmaxf(s2, s3)));             \
      float t0 = s0 - mx, t1 = s1 - mx, t2 = s2 - mx, t3 = s3 - mx;         \
      float e0 = __expf(t0), e1 = __expf(t1);                               \
      float e2 = __expf(t2), e3 = __expf(t3);                               \
      float S0 = rowsum16((e0 + e1) + (e2 + e3));                           \
      float S1 = rowsum16((t0 * e0 + t1 * e1) + (t2 * e2 + t3 * e3));       \
      float H = __logf(S0) - S1 / S0;                                       \
      hacc += (lid == 0) ? H : 0.0f;                                        \
    }                                                                       \
  } while (0)

// 512 blocks x 256 thr = 2 blocks/CU, all resident (single batch). 8 tiles/
// wave, rolling depth-4 pipeline. NEW: the first 4 tiles' loads are issued
// BEFORE the prep preamble, so the kernel-start HBM burst queues and drains
// under prep instead of in front of the first PACKX.
__launch_bounds__(256, 2)
__global__ void main_kernel(const float* __restrict__ x, const float* __restrict__ m,
                            float* ws, int totalWaves) {
  __shared__ short8 bsm[1024];        // 16 KB: bf16(2*m), chunk-swizzled
  __shared__ float mnorms[K];
  __shared__ char asmem[4][4096];     // per-wave A staging tiles

  const int tid  = threadIdx.x;
  const int lane = tid & 63;
  const int wid  = tid >> 6;
  const int wave = blockIdx.x * 4 + wid;
  const int W = totalWaves;           // 2048: tiles wave + k*W, k = 0..7 exact

  // ---- issue the first 4 tiles' loads immediately (independent of prep) ----
  f32x4 ld0[8], ld1[8], ld2[8], ld3[8];
  LOADX(ld0, wave);
  LOADX(ld1, wave + W);
  LOADX(ld2, wave + 2 * W);
  LOADX(ld3, wave + 3 * W);

  // ---- prep runs while those 32 KB/wave are in flight ----
  const f32x4* mv4 = (const f32x4*)m;
#pragma unroll
  for (int i0 = 0; i0 < (K * D) / 4; i0 += 256) {
    int i = i0 + tid;
    f32x4 v = mv4[i];
    int c = i >> 1, h = i & 1;          // 16B chunk / half within chunk
    int cs = c ^ ((c >> 4) & 7);        // row-XOR chunk swizzle
    int2v s;
    s[0] = cvt_pk_bf16(2.f * v[0], 2.f * v[1]);
    s[1] = cvt_pk_bf16(2.f * v[2], 2.f * v[3]);
    *(int2v*)((char*)bsm + cs * 16 + h * 8) = s;
  }
  // mnorm: 4 threads per row (tid = row*4 + part), 8 f32x4 each, pairwise
  // cross-lane reduce via shfl_xor over the 2 low lane bits.
  {
    int row = tid >> 2, part = tid & 3;
    const f32x4* mr = (const f32x4*)(m + row * D) + part * 8;
    float s = 0.f;
#pragma unroll
    for (int i = 0; i < 8; ++i) {
      f32x4 v = mr[i];
      s += (v[0] * v[0] + v[1] * v[1]) + (v[2] * v[2] + v[3] * v[3]);
    }
    s += __shfl_xor(s, 1, 64);
    s += __shfl_xor(s, 2, 64);
    if (part == 0 && row < K) mnorms[row] = s;
  }
  __syncthreads();

  const int lid  = lane & 15;   // A row / B col / C-D col (j)
  const int quad = lane >> 4;   // k group; C/D row = quad*4+reg
  char* amem = asmem[wid];

  float mn[4];
#pragma unroll
  for (int jt = 0; jt < 4; ++jt) mn[jt] = mnorms[jt * 16 + lid];

  int cbase[4], ra[4];
#pragma unroll
  for (int kk = 0; kk < 4; ++kk) {
    cbase[kk] = (lid * 16 + kk * 4 + quad) ^ (lid & 7);
    ra[kk] = lid * 256 + ((((kk << 2) | quad) ^ lid) << 4);
  }

  // A-stage write constants: load p gives lane i floats p*256 + i*4..+3
  //   row r = 2p + (i>>5), chunk c = (i&31)>>1, half h = i&1
  const int hi = lane >> 5;
  const int wc = (lane & 31) >> 1;
  const int wh = lane & 1;

  float hacc = 0.f;

  // rolling steady state: wait vmcnt(24), pack, refill, compute
  PACKX(ld0); LOADX(ld0, wave + 4 * W); TILE_COMPUTE();
  PACKX(ld1); LOADX(ld1, wave + 5 * W); TILE_COMPUTE();
  PACKX(ld2); LOADX(ld2, wave + 6 * W); TILE_COMPUTE();
  PACKX(ld3); LOADX(ld3, wave + 7 * W); TILE_COMPUTE();
  // drain
  PACKX(ld0); TILE_COMPUTE();
  PACKX(ld1); TILE_COMPUTE();
  PACKX(ld2); TILE_COMPUTE();
  PACKX(ld3); TILE_COMPUTE();

  // wave reduce -> block reduce -> one plain store per block (no atomic, no
  // ws pre-zero: ws[blockIdx.x] is overwritten before final reads it)
  for (int off = 1; off < 64; off <<= 1) hacc += __shfl_xor(hacc, off, 64);
  __shared__ float red[4];
  if (lane == 0) red[wid] = hacc;
  __syncthreads();
  if (tid == 0) ws[blockIdx.x] = red[0] + red[1] + red[2] + red[3];
}

__global__ void final_kernel(const float* __restrict__ m, const float* ws, float* out,
                             int nRows, int nBlocks) {
  __shared__ float mu[D];
  int lane = threadIdx.x;  // 64 threads
  for (int d = lane; d < D; d += 64) {
    float s = 0.f;
    for (int j = 0; j < K; ++j) s += m[j * D + d];
    mu[d] = s * (1.0f / K);
  }
  __syncthreads();

  // sum per-block partials of the intra entropy
  float part = 0.f;
  for (int i = lane; i < nBlocks; i += 64) part += ws[i];
  for (int off = 1; off < 64; off <<= 1) part += __shfl_xor(part, off, 64);

  const float* mr = m + lane * D;
  float dot = 0.f, nrm = 0.f;
  for (int d = 0; d < D; ++d) {
    dot += mu[d] * mr[d];
    nrm += mr[d] * mr[d];
  }
  float s = 2.f * dot - nrm;  // shift-invariant: drop ||mu||^2
  float mx = s;
  for (int off = 1; off < 64; off <<= 1) mx = fmaxf(mx, __shfl_xor(mx, off, 64));
  float t = s - mx;
  float e = __expf(t);
  float S0 = e, S1 = t * e;
  for (int off = 1; off < 64; off <<= 1) {
    S0 += __shfl_xor(S0, off, 64);
    S1 += __shfl_xor(S1, off, 64);
  }
  float inter = __logf(S0) - S1 / S0;
  if (lane == 0) {
    float intra = part / (float)nRows;
    out[0] = intra - inter;  // LAMB = 1
    out[1] = intra;
    out[2] = inter;
  }
}

extern "C" void kernel_launch(void* const* d_in, const int* in_sizes, int n_in,
                              void* d_out, int out_size, void* d_ws, size_t ws_size,
                              hipStream_t stream) {
  const float* x = (const float*)d_in[0];
  const float* m = (const float*)d_in[1];
  float* ws = (float*)d_ws;
  float* out = (float*)d_out;
  const int N = in_sizes[0] / D;       // 262144

  const int blocks = 512;              // 2 blocks/CU, single fully-resident batch
  const int totalWaves = blocks * 4;   // 2048 waves x exactly 8 tiles = 16384
  main_kernel<<<blocks, 256, 0, stream>>>(x, m, ws, totalWaves);

  final_kernel<<<1, 64, 0, stream>>>(m, ws, out, N, blocks);
}

// Round 9
// 187.915 us; speedup vs baseline: 1.0110x; 1.0110x over previous
//
#include <hip/hip_runtime.h>

#define D 128
#define K 64

typedef __attribute__((ext_vector_type(8))) short short8;   // 8 bf16 in 4 VGPRs
typedef __attribute__((ext_vector_type(2))) int int2v;      // 4 bf16 in 2 VGPRs
typedef __attribute__((ext_vector_type(4))) float f32x4;

// HW packed f32x2 -> bf16x2 (RNE). No builtin on gfx950 -> asm.
__device__ inline int cvt_pk_bf16(float lo, float hi) {
  int r;
  asm("v_cvt_pk_bf16_f32 %0, %1, %2" : "=v"(r) : "v"(lo), "v"(hi));
  return r;
}

// DPP row_ror allreduce (16-lane rows = lid groups). Pure VALU, no DS pipe.
template<int CTRL>
__device__ inline float dpp_ror(float x) {
  return __builtin_bit_cast(float, __builtin_amdgcn_update_dpp(
      0, __builtin_bit_cast(int, x), CTRL, 0xF, 0xF, true));
}
__device__ inline float rowsum16(float v) {
  v += dpp_ror<0x121>(v);
  v += dpp_ror<0x122>(v);
  v += dpp_ror<0x124>(v);
  v += dpp_ror<0x128>(v);
  return v;
}
__device__ inline float rowmax16(float v) {
  v = fmaxf(v, dpp_ror<0x121>(v));
  v = fmaxf(v, dpp_ror<0x122>(v));
  v = fmaxf(v, dpp_ror<0x124>(v));
  v = fmaxf(v, dpp_ror<0x128>(v));
  return v;
}

// Load tile t's 16x128 f32 rows, fully coalesced AND non-temporal: x is
// streamed exactly once; nt keeps the fill's dirty L2/L3 lines in place so
// HBM serves pure reads during main (round-7 confirmed: -11 us).
#define LOADX(dst, t) do {                                                  \
    const f32x4* xb = (const f32x4*)(x + (size_t)(t) * (16 * D)) + lane;    \
    _Pragma("unroll") for (int p = 0; p < 8; ++p)                           \
      dst[p] = __builtin_nontemporal_load(xb + p * 64);                     \
  } while (0)

// Pack f32->bf16 and stage into this wave's LDS tile (row-XOR chunk swizzle).
#define PACKX(src) do {                                                     \
    _Pragma("unroll") for (int p = 0; p < 8; ++p) {                         \
      f32x4 v = src[p];                                                     \
      int2v s;                                                              \
      s[0] = cvt_pk_bf16(v[0], v[1]);                                       \
      s[1] = cvt_pk_bf16(v[2], v[3]);                                       \
      int r = 2 * p + hi;                                                   \
      *(int2v*)(amem + r * 256 + ((wc ^ r) << 4) + wh * 8) = s;             \
    }                                                                       \
  } while (0)

// ds_read A fragments, 16 MFMA, online-entropy epilogue -> hacc.
#define TILE_COMPUTE() do {                                                 \
    f32x4 acc[4];                                                           \
    _Pragma("unroll") for (int jt = 0; jt < 4; ++jt)                        \
      acc[jt] = (f32x4){0.f, 0.f, 0.f, 0.f};                                \
    _Pragma("unroll") for (int kk = 0; kk < 4; ++kk) {                      \
      short8 afrag = *(const short8*)(amem + ra[kk]);                       \
      _Pragma("unroll") for (int jt = 0; jt < 4; ++jt)                      \
        acc[jt] = __builtin_amdgcn_mfma_f32_16x16x32_bf16(                  \
            afrag, bsm[cbase[kk] + jt * 256], acc[jt], 0, 0, 0);            \
    }                                                                       \
    _Pragma("unroll") for (int r = 0; r < 4; ++r) {                         \
      float s0 = acc[0][r] - mn[0];                                         \
      float s1 = acc[1][r] - mn[1];                                         \
      float s2 = acc[2][r] - mn[2];                                         \
      float s3 = acc[3][r] - mn[3];                                         \
      float mx = rowmax16(fmaxf(fmaxf(s0, s1), fmaxf(s2, s3)));             \
      float t0 = s0 - mx, t1 = s1 - mx, t2 = s2 - mx, t3 = s3 - mx;         \
      float e0 = __expf(t0), e1 = __expf(t1);                               \
      float e2 = __expf(t2), e3 = __expf(t3);                               \
      float S0 = rowsum16((e0 + e1) + (e2 + e3));                           \
      float S1 = rowsum16((t0 * e0 + t1 * e1) + (t2 * e2 + t3 * e3));       \
      float H = __logf(S0) - S1 / S0;                                       \
      hacc += (lid == 0) ? H : 0.0f;                                        \
    }                                                                       \
  } while (0)

// Single-batch residency: 512 blocks x 256 thr = 2 blocks/CU, ALL resident.
// 8 tiles/wave, rolling depth-4 pipeline: 24 loads (24 KB) in flight per wave
// continuously, never draining to vmcnt(0) until the final 4 tiles.
__launch_bounds__(256, 2)
__global__ void main_kernel(const float* __restrict__ x, const float* __restrict__ m,
                            float* ws, int totalWaves) {
  __shared__ short8 bsm[1024];        // 16 KB: bf16(2*m), chunk-swizzled
  __shared__ float mnorms[K];
  __shared__ char asmem[4][4096];     // per-wave A staging tiles

  const int tid = threadIdx.x;

  // Block-local prep, vectorized (f32x4). m is 32 KB, L2/L3-served.
  const f32x4* mv4 = (const f32x4*)m;
#pragma unroll
  for (int i0 = 0; i0 < (K * D) / 4; i0 += 256) {
    int i = i0 + tid;
    f32x4 v = mv4[i];
    int c = i >> 1, h = i & 1;          // 16B chunk / half within chunk
    int cs = c ^ ((c >> 4) & 7);        // row-XOR chunk swizzle
    int2v s;
    s[0] = cvt_pk_bf16(2.f * v[0], 2.f * v[1]);
    s[1] = cvt_pk_bf16(2.f * v[2], 2.f * v[3]);
    *(int2v*)((char*)bsm + cs * 16 + h * 8) = s;
  }
  if (tid < K) {
    const f32x4* mr = (const f32x4*)(m + tid * D);
    float s = 0.f;
#pragma unroll
    for (int i = 0; i < 32; ++i) {
      f32x4 v = mr[i];
      s += (v[0] * v[0] + v[1] * v[1]) + (v[2] * v[2] + v[3] * v[3]);
    }
    mnorms[tid] = s;
  }
  __syncthreads();

  const int lane = tid & 63;
  const int lid  = lane & 15;   // A row / B col / C-D col (j)
  const int quad = lane >> 4;   // k group; C/D row = quad*4+reg
  const int wid  = tid >> 6;
  char* amem = asmem[wid];

  float mn[4];
#pragma unroll
  for (int jt = 0; jt < 4; ++jt) mn[jt] = mnorms[jt * 16 + lid];

  int cbase[4], ra[4];
#pragma unroll
  for (int kk = 0; kk < 4; ++kk) {
    cbase[kk] = (lid * 16 + kk * 4 + quad) ^ (lid & 7);
    ra[kk] = lid * 256 + ((((kk << 2) | quad) ^ lid) << 4);
  }

  // A-stage write constants: load p gives lane i floats p*256 + i*4..+3
  //   row r = 2p + (i>>5), chunk c = (i&31)>>1, half h = i&1
  const int hi = lane >> 5;
  const int wc = (lane & 31) >> 1;
  const int wh = lane & 1;

  const int wave = blockIdx.x * 4 + wid;
  const int W = totalWaves;           // 2048: tiles wave + k*W, k = 0..7 exact
  float hacc = 0.f;

  f32x4 ld0[8], ld1[8], ld2[8], ld3[8];
  LOADX(ld0, wave);
  LOADX(ld1, wave + W);
  LOADX(ld2, wave + 2 * W);
  LOADX(ld3, wave + 3 * W);

  // rolling steady state: wait vmcnt(24), pack, refill, compute
  PACKX(ld0); LOADX(ld0, wave + 4 * W); TILE_COMPUTE();
  PACKX(ld1); LOADX(ld1, wave + 5 * W); TILE_COMPUTE();
  PACKX(ld2); LOADX(ld2, wave + 6 * W); TILE_COMPUTE();
  PACKX(ld3); LOADX(ld3, wave + 7 * W); TILE_COMPUTE();
  // drain
  PACKX(ld0); TILE_COMPUTE();
  PACKX(ld1); TILE_COMPUTE();
  PACKX(ld2); TILE_COMPUTE();
  PACKX(ld3); TILE_COMPUTE();

  // wave reduce -> block reduce -> one plain store per block (no atomic, no
  // ws pre-zero: ws[blockIdx.x] is overwritten before final reads it)
  for (int off = 1; off < 64; off <<= 1) hacc += __shfl_xor(hacc, off, 64);
  __shared__ float red[4];
  if (lane == 0) red[wid] = hacc;
  __syncthreads();
  if (tid == 0) ws[blockIdx.x] = red[0] + red[1] + red[2] + red[3];
}

__global__ void final_kernel(const float* __restrict__ m, const float* ws, float* out,
                             int nRows, int nBlocks) {
  __shared__ float mu[D];
  int lane = threadIdx.x;  // 64 threads
  for (int d = lane; d < D; d += 64) {
    float s = 0.f;
    for (int j = 0; j < K; ++j) s += m[j * D + d];
    mu[d] = s * (1.0f / K);
  }
  __syncthreads();

  // sum per-block partials of the intra entropy
  float part = 0.f;
  for (int i = lane; i < nBlocks; i += 64) part += ws[i];
  for (int off = 1; off < 64; off <<= 1) part += __shfl_xor(part, off, 64);

  const float* mr = m + lane * D;
  float dot = 0.f, nrm = 0.f;
  for (int d = 0; d < D; ++d) {
    dot += mu[d] * mr[d];
    nrm += mr[d] * mr[d];
  }
  float s = 2.f * dot - nrm;  // shift-invariant: drop ||mu||^2
  float mx = s;
  for (int off = 1; off < 64; off <<= 1) mx = fmaxf(mx, __shfl_xor(mx, off, 64));
  float t = s - mx;
  float e = __expf(t);
  float S0 = e, S1 = t * e;
  for (int off = 1; off < 64; off <<= 1) {
    S0 += __shfl_xor(S0, off, 64);
    S1 += __shfl_xor(S1, off, 64);
  }
  float inter = __logf(S0) - S1 / S0;
  if (lane == 0) {
    float intra = part / (float)nRows;
    out[0] = intra - inter;  // LAMB = 1
    out[1] = intra;
    out[2] = inter;
  }
}

extern "C" void kernel_launch(void* const* d_in, const int* in_sizes, int n_in,
                              void* d_out, int out_size, void* d_ws, size_t ws_size,
                              hipStream_t stream) {
  const float* x = (const float*)d_in[0];
  const float* m = (const float*)d_in[1];
  float* ws = (float*)d_ws;
  float* out = (float*)d_out;
  const int N = in_sizes[0] / D;       // 262144

  const int blocks = 512;              // 2 blocks/CU, single fully-resident batch
  const int totalWaves = blocks * 4;   // 2048 waves x exactly 8 tiles = 16384
  main_kernel<<<blocks, 256, 0, stream>>>(x, m, ws, totalWaves);

  final_kernel<<<1, 64, 0, stream>>>(m, ws, out, N, blocks);
}